// Round 5
// baseline (972.106 us; speedup 1.0000x reference)
//
#include <hip/hip_runtime.h>

// GRU, T=4096, B=256, I=2, H=32, O=1. Only batch row 255 reaches the output.
// Single-wave sequential recurrence; latency/issue-bound.
//
// R8: R7 == R5 exactly (VGPR=84, ~910us) -> pins don't matter; the register
// BUDGET is capped. Diagnosis: __launch_bounds__(64,1) sets only the
// waves-per-EU MINIMUM (=1, max stays 8); merged with amdgpu_waves_per_eu(1,1)
// the launch-bounds range wins and the scheduler targets 8 waves/EU ->
// 512/8 = 64-VGPR budget (R3's VGPR=64 is exactly that; R5/R7's 84 is the
// scheduler settling partway). It then sinks/remats the 96 weight loads into
// the loop no matter how we pin. Fix: REMOVE __launch_bounds__; declare only
// amdgpu_flat_work_group_size(64,64) + amdgpu_waves_per_eu(1,1) so the
// occupancy target is unambiguously 1 wave/EU -> 512-VGPR budget.
// Math is bit-identical to R5/R7 (absmax=0 in both passing runs):
// DPP 15/7/2/1 butterfly trees, one-step-early ds_swizzle xor16 partner
// recompute, pre-scaled weights, rcp/exp2 activations.

#define TT 4096

typedef float v2f __attribute__((ext_vector_type(2)));

__device__ __forceinline__ v2f fma2(v2f a, v2f b, v2f c) {
    return __builtin_elementwise_fma(a, b, c);
}
__device__ __forceinline__ float rl(float v, int l) {
    return __int_as_float(__builtin_amdgcn_readlane(__float_as_int(v), l));
}
__device__ __forceinline__ float fexp2(float x) { return __builtin_amdgcn_exp2f(x); }
__device__ __forceinline__ float frcp(float x)  { return __builtin_amdgcn_rcpf(x); }
// volatile: may not be deleted, duplicated, or sunk into the loop.
__device__ __forceinline__ float pin(float x)   { asm volatile("" : "+v"(x)); return x; }

#define DPP_X1  0xB1   // quad_perm [1,0,3,2] : lane ^= 1
#define DPP_X2  0x4E   // quad_perm [2,3,0,1] : lane ^= 2
#define DPP_X7  0x141  // row_half_mirror     : lane ^= 7
#define DPP_X15 0x140  // row_mirror          : lane ^= 15

template<int CTRL>
__device__ __forceinline__ float dppf(float x) {
    return __int_as_float(__builtin_amdgcn_mov_dpp(__float_as_int(x), CTRL, 0xF, 0xF, false));
}

#define NLOG2E  (-1.44269504088896340736f)   // r/z dots pre-scaled by this
#define TLOG2E  ( 2.88539008177792681472f)   // n dot pre-scaled by this

__global__
__attribute__((amdgpu_flat_work_group_size(64, 64), amdgpu_waves_per_eu(1, 1)))
void gru_seq(
    const float* __restrict__ x,
    const float* __restrict__ w_ih,
    const float* __restrict__ w_hh,
    const float* __restrict__ b_ih,
    const float* __restrict__ b_hh,
    float* __restrict__ hbuf)
{
    const int lane = threadIdx.x;
    const int low  = lane & 31;
    const int rrow = low;        // r gate row
    const int zrow = 32 + low;   // z gate row
    const int nrow = 64 + low;   // n gate row

    // --- xor-permutation map: tree register i holds h[low ^ sig[i]] ---
    // tree0 (i<16) seeded by h[low]; tree1 (i>=16) seeded by h[low^16].
    // cascade: bit0->^15, bit1->^7, bit2->^2, bit3->^1 (DPP-reachable masks).
    int sig[32];
#pragma unroll
    for (int i2 = 0; i2 < 32; ++i2) {
        int b = i2 & 15;
        int s = (i2 & 16) ? 16 : 0;
        if (b & 1) s ^= 15;
        if (b & 2) s ^= 7;
        if (b & 4) s ^= 2;
        if (b & 8) s ^= 1;
        sig[i2] = s;
    }

    // --- weights, pre-scaled and pre-permuted per lane; PINNED in VGPRs ---
    v2f wr[16], wz[16], wn[16];
#pragma unroll
    for (int p = 0; p < 16; ++p) {
        const int c0 = low ^ sig[2 * p], c1 = low ^ sig[2 * p + 1];
        v2f a = { w_hh[rrow * 32 + c0], w_hh[rrow * 32 + c1] };
        v2f b = { w_hh[zrow * 32 + c0], w_hh[zrow * 32 + c1] };
        v2f c = { w_hh[nrow * 32 + c0], w_hh[nrow * 32 + c1] };
        a *= NLOG2E;  b *= NLOG2E;  c *= TLOG2E;
        wr[p].x = pin(a.x); wr[p].y = pin(a.y);
        wz[p].x = pin(b.x); wz[p].y = pin(b.y);
        wn[p].x = pin(c.x); wn[p].y = pin(c.y);
    }
    const float wir0 = pin(w_ih[rrow * 2 + 0] * NLOG2E);
    const float wir1 = pin(w_ih[rrow * 2 + 1] * NLOG2E);
    const float wiz0 = pin(w_ih[zrow * 2 + 0] * NLOG2E);
    const float wiz1 = pin(w_ih[zrow * 2 + 1] * NLOG2E);
    const float win0 = pin(w_ih[nrow * 2 + 0] * TLOG2E);
    const float win1 = pin(w_ih[nrow * 2 + 1] * TLOG2E);
    const float bsr  = pin((b_ih[rrow] + b_hh[rrow]) * NLOG2E);
    const float bsz  = pin((b_ih[zrow] + b_hh[zrow]) * NLOG2E);
    const float bin_ = pin(b_ih[nrow] * TLOG2E);   // outside r*(...)
    const float bhn  = pin(b_hh[nrow] * TLOG2E);   // inside  r*(...)

    float h_el   = 0.0f;   // h[low], identical across wave halves
    float g1prev = 0.0f;   // h[low^16] of previous step
    float zz16   = 0.0f;   // partner's z  (via ds_swizzle xor16, prev step)
    float nv16   = 0.0f;   // partner's n  (via ds_swizzle xor16, prev step)
    float hacc[2];         // 2-step store batch (float2)

    // x[t, 255, 0:2] as float2 at index t*256+255; 64 steps per lane-load,
    // prefetched one block ahead.
    const float2* xp = (const float2*)x;
    float2 xv = xp[(size_t)lane * 256 + 255];

    for (int tb = 0; tb < 64; ++tb) {
        float2 xv_next = xv;
        if (tb < 63) xv_next = xp[((size_t)(tb + 1) * 64 + lane) * 256 + 255];
        float2* hout = (float2*)(hbuf + (size_t)low * TT + tb * 64);

#pragma unroll 2
        for (int i = 0; i < 64; ++i) {
            // ---- tree0: replicate own 16-block of h via DPP butterfly ----
            float t0[16];
            t0[0] = h_el;
            t0[1] = dppf<DPP_X15>(t0[0]);
            t0[2] = dppf<DPP_X7>(t0[0]);  t0[3] = dppf<DPP_X7>(t0[1]);
#pragma unroll
            for (int b = 0; b < 4; ++b) t0[4 + b] = dppf<DPP_X2>(t0[b]);
#pragma unroll
            for (int b = 0; b < 8; ++b) t0[8 + b] = dppf<DPP_X1>(t0[b]);

            const float x0 = rl(xv.x, i);
            const float x1 = rl(xv.y, i);
            const float br = fmaf(x1, wir1, fmaf(x0, wir0, bsr));   // scaled
            const float bz = fmaf(x1, wiz1, fmaf(x0, wiz0, bsz));   // scaled
            const float xn = fmaf(x1, win1, fmaf(x0, win0, bin_));  // scaled

            // ---- dots over tree0 while the (prev-step) swizzles land ----
            v2f ar0 = {br,  0.0f}, ar1 = {0.0f, 0.0f};
            v2f az0 = {bz,  0.0f}, az1 = {0.0f, 0.0f};
            v2f an0 = {bhn, 0.0f}, an1 = {0.0f, 0.0f};
#pragma unroll
            for (int p = 0; p < 8; p += 2) {
                v2f ha = {t0[2 * p],     t0[2 * p + 1]};
                v2f hb = {t0[2 * p + 2], t0[2 * p + 3]};
                ar0 = fma2(ha, wr[p],     ar0);
                ar1 = fma2(hb, wr[p + 1], ar1);
                az0 = fma2(ha, wz[p],     az0);
                az1 = fma2(hb, wz[p + 1], az1);
                an0 = fma2(ha, wn[p],     an0);
                an1 = fma2(hb, wn[p + 1], an1);
            }

            // ---- tree1: partner h[low^16] recomputed bitwise-exactly ----
            const float g1 = fmaf(zz16, g1prev - nv16, nv16);
            g1prev = g1;
            float t1[16];
            t1[0] = g1;
            t1[1] = dppf<DPP_X15>(t1[0]);
            t1[2] = dppf<DPP_X7>(t1[0]);  t1[3] = dppf<DPP_X7>(t1[1]);
#pragma unroll
            for (int b = 0; b < 4; ++b) t1[4 + b] = dppf<DPP_X2>(t1[b]);
#pragma unroll
            for (int b = 0; b < 8; ++b) t1[8 + b] = dppf<DPP_X1>(t1[b]);

#pragma unroll
            for (int p = 0; p < 8; p += 2) {
                v2f ha = {t1[2 * p],     t1[2 * p + 1]};
                v2f hb = {t1[2 * p + 2], t1[2 * p + 3]};
                ar0 = fma2(ha, wr[8 + p],     ar0);
                ar1 = fma2(hb, wr[8 + p + 1], ar1);
                az0 = fma2(ha, wz[8 + p],     az0);
                az1 = fma2(hb, wz[8 + p + 1], az1);
                an0 = fma2(ha, wn[8 + p],     an0);
                an1 = fma2(hb, wn[8 + p + 1], an1);
            }

            v2f sr = ar0 + ar1;
            v2f sz = az0 + az1;
            v2f sn = an0 + an1;
            const float pr   = sr.x + sr.y;   // -log2e * (r pre-act)
            const float pz   = sz.x + sz.y;   // -log2e * (z pre-act)
            const float hn_s = sn.x + sn.y;   // 2log2e * (n hidden dot + b_hh)

            const float rr = frcp(1.0f + fexp2(pr));   // sigmoid(r)
            const float zz = frcp(1.0f + fexp2(pz));   // sigmoid(z)
            zz16 = __int_as_float(__builtin_amdgcn_ds_swizzle(__float_as_int(zz), 0x401F));

            // n = tanh(xn + r*hn); arg pre-scaled by 2log2e
            const float nv = fmaf(-2.0f, frcp(1.0f + fexp2(fmaf(rr, hn_s, xn))), 1.0f);
            nv16 = __int_as_float(__builtin_amdgcn_ds_swizzle(__float_as_int(nv), 0x401F));

            h_el = fmaf(zz, h_el - nv, nv);     // h = n + z*(h-n)

            hacc[i & 1] = h_el;
            if ((i & 1) == 1) hout[i >> 1] = *(const float2*)hacc;
        }
        xv = xv_next;
    }
}

// out[t] = sum_j hbuf[j*TT + t] * w_fc[j] + b_fc   (transposed hbuf)
__global__ void fc_out(const float* __restrict__ hbuf,
                       const float* __restrict__ w_fc,
                       const float* __restrict__ b_fc,
                       float* __restrict__ out)
{
    const int t = blockIdx.x * blockDim.x + threadIdx.x;
    if (t >= TT) return;
    float acc = 0.f;
#pragma unroll
    for (int j = 0; j < 32; ++j) acc = fmaf(hbuf[j * TT + t], w_fc[j], acc);
    out[t] = acc + b_fc[0];
}

extern "C" void kernel_launch(void* const* d_in, const int* in_sizes, int n_in,
                              void* d_out, int out_size, void* d_ws, size_t ws_size,
                              hipStream_t stream) {
    const float* x    = (const float*)d_in[0];
    const float* w_ih = (const float*)d_in[1];
    const float* w_hh = (const float*)d_in[2];
    const float* b_ih = (const float*)d_in[3];
    const float* b_hh = (const float*)d_in[4];
    const float* w_fc = (const float*)d_in[5];
    const float* b_fc = (const float*)d_in[6];
    float* out  = (float*)d_out;
    float* hbuf = (float*)d_ws;   // 32*TT*4 = 512 KB

    gru_seq<<<1, 64, 0, stream>>>(x, w_ih, w_hh, b_ih, b_hh, hbuf);
    fc_out<<<TT / 256, 256, 0, stream>>>(hbuf, w_fc, b_fc, out);
}

// Round 6
// 864.958 us; speedup vs baseline: 1.1239x; 1.1239x over previous
//
#include <hip/hip_runtime.h>

// GRU, T=4096, B=256, I=2, H=32, O=1. Only batch row 255 reaches the output.
// Single-wave sequential recurrence; latency-bound on the h->h dependency cycle.
//
// R9: R8 proved the kernel is chain-latency-bound (VGPR 84->132 with weights
// resident: zero time change). Chain comparison across rounds:
//   R3 (LDS broadcast + shfl_xor32)        = 417 cy/step
//   R5/R7/R8 (DPP trees + g1 swizzles)     = 533 cy/step
// -> dependent DPP trees are SLOWER than one LDS broadcast; and R3 still
// carries a second LDS-pipe round-trip (shfl_xor = ds_bpermute, ~110 cy) dead
// on the serial cycle. This version = R3's skeleton with the shfl removed:
// each lane computes ALL THREE gate rows (low, 32+low, 64+low — R5-verified,
// absmax=0) so sigmoid/tanh/h' are lane-local. No cross-lane ops after the
// broadcast. Extra dot issue (48 vs 32 fma2) hides under the LDS-read stall.
// Cycle: h' -> ds_write -> 8x ds_read_b128 (~120) -> dots (~60) -> sums ->
// sigmoid(r) (~50) -> tanh(n) (~55) -> h'  ~= 300-330 cy/step.

#define TT 4096

typedef float v2f __attribute__((ext_vector_type(2)));

__device__ __forceinline__ v2f fma2(v2f a, v2f b, v2f c) {
    return __builtin_elementwise_fma(a, b, c);
}
__device__ __forceinline__ float rl(float v, int l) {
    return __int_as_float(__builtin_amdgcn_readlane(__float_as_int(v), l));
}
__device__ __forceinline__ float fexp2(float x) { return __builtin_amdgcn_exp2f(x); }
__device__ __forceinline__ float frcp(float x)  { return __builtin_amdgcn_rcpf(x); }
// volatile: may not be deleted, duplicated, or sunk into the loop.
__device__ __forceinline__ float pin(float x)   { asm volatile("" : "+v"(x)); return x; }

#define NLOG2E  (-1.44269504088896340736f)   // r/z dots pre-scaled by this
#define TLOG2E  ( 2.88539008177792681472f)   // n dot pre-scaled by this

__global__
__attribute__((amdgpu_flat_work_group_size(64, 64), amdgpu_waves_per_eu(1, 1)))
void gru_seq(
    const float* __restrict__ x,
    const float* __restrict__ w_ih,
    const float* __restrict__ w_hh,
    const float* __restrict__ b_ih,
    const float* __restrict__ b_hh,
    float* __restrict__ hbuf)
{
    __shared__ float hsm[64];

    const int lane = threadIdx.x;
    const int low  = lane & 31;
    const int rrow = low;        // r gate row
    const int zrow = 32 + low;   // z gate row
    const int nrow = 64 + low;   // n gate row

    // --- weights: 3 rows x 32 cols per lane, natural column order, scaled ---
    const v2f* w_hh2 = (const v2f*)w_hh;
    v2f wr[16], wz[16], wn[16];
#pragma unroll
    for (int k = 0; k < 16; ++k) {
        v2f a = w_hh2[rrow * 16 + k] * NLOG2E;
        v2f b = w_hh2[zrow * 16 + k] * NLOG2E;
        v2f c = w_hh2[nrow * 16 + k] * TLOG2E;
        wr[k].x = pin(a.x); wr[k].y = pin(a.y);
        wz[k].x = pin(b.x); wz[k].y = pin(b.y);
        wn[k].x = pin(c.x); wn[k].y = pin(c.y);
    }
    const float wir0 = pin(w_ih[rrow * 2 + 0] * NLOG2E);
    const float wir1 = pin(w_ih[rrow * 2 + 1] * NLOG2E);
    const float wiz0 = pin(w_ih[zrow * 2 + 0] * NLOG2E);
    const float wiz1 = pin(w_ih[zrow * 2 + 1] * NLOG2E);
    const float win0 = pin(w_ih[nrow * 2 + 0] * TLOG2E);
    const float win1 = pin(w_ih[nrow * 2 + 1] * TLOG2E);
    const float bsr  = pin((b_ih[rrow] + b_hh[rrow]) * NLOG2E);
    const float bsz  = pin((b_ih[zrow] + b_hh[zrow]) * NLOG2E);
    const float bin_ = pin(b_ih[nrow] * TLOG2E);   // outside r*(...)
    const float bhn  = pin(b_hh[nrow] * TLOG2E);   // inside  r*(...)

    hsm[lane] = 0.0f;          // single wave: DS pipe in-order, no barrier
    float h_el = 0.0f;         // this lane's h[low]
    float hacc[4];             // 4-step store batch (float4)

    // x[t, 255, 0:2] as float2 at index t*256+255; 64 steps per lane-load,
    // prefetched one block ahead.
    const float2* xp = (const float2*)x;
    float2 xv = xp[(size_t)lane * 256 + 255];

    const float4* h4 = (const float4*)hsm;

    for (int tb = 0; tb < 64; ++tb) {
        float2 xv_next = xv;
        if (tb < 63) xv_next = xp[((size_t)(tb + 1) * 64 + lane) * 256 + 255];
        // transposed layout: hbuf[j*TT + t], t = tb*64 + i
        float4* hout = (float4*)(hbuf + (size_t)low * TT + tb * 64);

#pragma unroll 4
        for (int i = 0; i < 64; ++i) {
            // broadcast-read h: 8 x ds_read_b128, all lanes same address
            float4 hq[8];
#pragma unroll
            for (int k = 0; k < 8; ++k) hq[k] = h4[k];

            const float x0 = rl(xv.x, i);
            const float x1 = rl(xv.y, i);
            const float br = fmaf(x1, wir1, fmaf(x0, wir0, bsr));   // scaled
            const float bz = fmaf(x1, wiz1, fmaf(x0, wiz0, bsz));   // scaled
            const float xn = fmaf(x1, win1, fmaf(x0, win0, bin_));  // scaled

            // r-dot first (it gates the serial chain), then z, then n
            v2f ar0 = {br, 0.0f}, ar1 = {0.0f, 0.0f};
#pragma unroll
            for (int k = 0; k < 8; ++k) {
                v2f hl = {hq[k].x, hq[k].y};
                v2f hh = {hq[k].z, hq[k].w};
                ar0 = fma2(hl, wr[2 * k],     ar0);
                ar1 = fma2(hh, wr[2 * k + 1], ar1);
            }
            v2f az0 = {bz, 0.0f}, az1 = {0.0f, 0.0f};
#pragma unroll
            for (int k = 0; k < 8; ++k) {
                v2f hl = {hq[k].x, hq[k].y};
                v2f hh = {hq[k].z, hq[k].w};
                az0 = fma2(hl, wz[2 * k],     az0);
                az1 = fma2(hh, wz[2 * k + 1], az1);
            }
            v2f an0 = {bhn, 0.0f}, an1 = {0.0f, 0.0f};
#pragma unroll
            for (int k = 0; k < 8; ++k) {
                v2f hl = {hq[k].x, hq[k].y};
                v2f hh = {hq[k].z, hq[k].w};
                an0 = fma2(hl, wn[2 * k],     an0);
                an1 = fma2(hh, wn[2 * k + 1], an1);
            }

            v2f sr = ar0 + ar1;
            v2f sz = az0 + az1;
            v2f sn = an0 + an1;
            const float pr   = sr.x + sr.y;   // -log2e * (r pre-act)
            const float pz   = sz.x + sz.y;   // -log2e * (z pre-act)
            const float hn_s = sn.x + sn.y;   // 2log2e * (n hidden dot + b_hh)

            const float rr = frcp(1.0f + fexp2(pr));   // sigmoid(r)
            const float zz = frcp(1.0f + fexp2(pz));   // sigmoid(z)

            // n = tanh(xn + r*hn); arg pre-scaled by 2log2e
            const float nv = fmaf(-2.0f, frcp(1.0f + fexp2(fmaf(rr, hn_s, xn))), 1.0f);
            h_el = fmaf(zz, h_el - nv, nv);     // h = n + z*(h-n)

            hsm[lane] = h_el;                   // publish for next step
            hacc[i & 3] = h_el;
            if ((i & 3) == 3) hout[i >> 2] = *(const float4*)hacc;
        }
        xv = xv_next;
    }
}

// out[t] = sum_j hbuf[j*TT + t] * w_fc[j] + b_fc   (transposed hbuf)
__global__ void fc_out(const float* __restrict__ hbuf,
                       const float* __restrict__ w_fc,
                       const float* __restrict__ b_fc,
                       float* __restrict__ out)
{
    const int t = blockIdx.x * blockDim.x + threadIdx.x;
    if (t >= TT) return;
    float acc = 0.f;
#pragma unroll
    for (int j = 0; j < 32; ++j) acc = fmaf(hbuf[j * TT + t], w_fc[j], acc);
    out[t] = acc + b_fc[0];
}

extern "C" void kernel_launch(void* const* d_in, const int* in_sizes, int n_in,
                              void* d_out, int out_size, void* d_ws, size_t ws_size,
                              hipStream_t stream) {
    const float* x    = (const float*)d_in[0];
    const float* w_ih = (const float*)d_in[1];
    const float* w_hh = (const float*)d_in[2];
    const float* b_ih = (const float*)d_in[3];
    const float* b_hh = (const float*)d_in[4];
    const float* w_fc = (const float*)d_in[5];
    const float* b_fc = (const float*)d_in[6];
    float* out  = (float*)d_out;
    float* hbuf = (float*)d_ws;   // 32*TT*4 = 512 KB

    gru_seq<<<1, 64, 0, stream>>>(x, w_ih, w_hh, b_ih, b_hh, hbuf);
    fc_out<<<TT / 256, 256, 0, stream>>>(hbuf, w_fc, b_fc, out);
}